// Round 2
// baseline (1141.521 us; speedup 1.0000x reference)
//
#include <hip/hip_runtime.h>

#define CAP 64
#define BN_EPS 1e-5f

__device__ __forceinline__ float bcast(float v, int lane) {
    return __int_as_float(__builtin_amdgcn_readlane(__float_as_int(v), lane));
}

// ---------------- bucket build: CSR-lite with fixed capacity ----------------
__global__ __launch_bounds__(256) void build_buckets(
    const int* __restrict__ ei, int E,
    int* __restrict__ deg, int* __restrict__ bucket)
{
    int e = blockIdx.x * blockDim.x + threadIdx.x;
    if (e >= E) return;
    int src = ei[e];
    int dst = ei[E + e];
    int slot = atomicAdd(&deg[dst], 1);
    if (slot < CAP) bucket[dst * CAP + slot] = src;
}

// ---------------- per-node u/v precompute: u = f@(A-B)+ba, v = f@B ----------
// wa is [2K][64] row-major. thread t: node = t>>1, half = t&1 (0:u, 1:v).
__global__ __launch_bounds__(256) void uv_kernel(
    const float* __restrict__ feat, int ldf, int K, int N,
    const float* __restrict__ wa, const float* __restrict__ ba,
    float* __restrict__ U, float* __restrict__ V)
{
    __shared__ float Wlds[2][64][64];
    __shared__ float blds[64];
    int tid = threadIdx.x;
    for (int idx = tid; idx < 2 * K * 64; idx += blockDim.x) {
        int half = idx / (K * 64);
        int rem = idx - half * (K * 64);
        int k = rem >> 6, o = rem & 63;
        float wB = wa[(K + k) * 64 + o];
        Wlds[half][k][o] = (half == 0) ? (wa[k * 64 + o] - wB) : wB;
    }
    if (tid < 64) blds[tid] = ba[tid];
    __syncthreads();

    int t = blockIdx.x * blockDim.x + tid;
    if (t >= 2 * N) return;
    int node = t >> 1, half = t & 1;

    float acc[64];
    #pragma unroll
    for (int o = 0; o < 64; ++o) acc[o] = (half == 0) ? blds[o] : 0.f;

    const float* f = feat + (long)node * ldf;
    for (int k = 0; k < K; ++k) {
        float c = f[k];
        #pragma unroll
        for (int o = 0; o < 64; ++o) acc[o] = fmaf(c, Wlds[half][k][o], acc[o]);
    }
    float* dstp = (half == 0 ? U : V) + (long)node * 64;
    #pragma unroll
    for (int o = 0; o < 64; o += 4)
        *(float4*)(dstp + o) = make_float4(acc[o], acc[o+1], acc[o+2], acc[o+3]);
}

// ---------------- node kernel: wave per node, lane = out channel ------------
// msg = relu(u[dst]+v[src]) @ wb + bb ; acc = max over edges; BN+ReLU fused.
__global__ __launch_bounds__(256) void node_kernel(
    const float* __restrict__ U, const float* __restrict__ V,
    const int* __restrict__ deg, const int* __restrict__ bucket,
    const float* __restrict__ wb, const float* __restrict__ bb,
    const float* __restrict__ bng, const float* __restrict__ bnb,
    const float* __restrict__ bnm, const float* __restrict__ bnv,
    int N, float* __restrict__ Fout)
{
    int lane = threadIdx.x & 63;
    int node = (blockIdx.x * blockDim.x + threadIdx.x) >> 6;
    if (node >= N) return;
    node = __builtin_amdgcn_readfirstlane(node);

    float wreg[64];
    #pragma unroll
    for (int k = 0; k < 64; ++k) wreg[k] = wb[k * 64 + lane];

    float u = U[(long)node * 64 + lane];
    int d = deg[node];
    if (d > CAP) d = CAP;

    float acc = -INFINITY;
    for (int s = 0; s < d; ++s) {
        int src = bucket[node * CAP + s];
        float vv = V[(long)src * 64 + lane];
        float c = fmaxf(u + vv, 0.f);
        float m0 = 0.f, m1 = 0.f, m2 = 0.f, m3 = 0.f;
        #pragma unroll
        for (int k = 0; k < 64; k += 4) {
            m0 = fmaf(bcast(c, k    ), wreg[k    ], m0);
            m1 = fmaf(bcast(c, k + 1), wreg[k + 1], m1);
            m2 = fmaf(bcast(c, k + 2), wreg[k + 2], m2);
            m3 = fmaf(bcast(c, k + 3), wreg[k + 3], m3);
        }
        float msg = (m0 + m1) + (m2 + m3);
        acc = fmaxf(acc, msg);
    }
    float aggv = (d > 0) ? (acc + bb[lane]) : 0.f;
    float bn = (aggv - bnm[lane]) * rsqrtf(bnv[lane] + BN_EPS) * bng[lane] + bnb[lane];
    Fout[(long)node * 64 + lane] = fmaxf(bn, 0.f);
}

// ---------------- dense head: thread per node -------------------------------
__global__ __launch_bounds__(256) void head_kernel(
    const float* __restrict__ F,
    const float* __restrict__ lw1, const float* __restrict__ lb1,
    const float* __restrict__ lw2, const float* __restrict__ lb2,
    const float* __restrict__ lw3, const float* __restrict__ lb3,
    const float* __restrict__ lw4, const float* __restrict__ lb4,
    int N, float* __restrict__ out)
{
    __shared__ float W1[64][64];
    __shared__ float W2[64][32];
    __shared__ float W3[32][16];
    __shared__ float W4[16][3];
    __shared__ float B1[64], B2[32], B3[16], B4[3];
    int tid = threadIdx.x;
    for (int i = tid; i < 64 * 64; i += blockDim.x) W1[i >> 6][i & 63] = lw1[i];
    for (int i = tid; i < 64 * 32; i += blockDim.x) W2[i >> 5][i & 31] = lw2[i];
    for (int i = tid; i < 32 * 16; i += blockDim.x) W3[i >> 4][i & 15] = lw3[i];
    for (int i = tid; i < 16 * 3;  i += blockDim.x) W4[i / 3][i % 3]  = lw4[i];
    if (tid < 64) B1[tid] = lb1[tid];
    if (tid < 32) B2[tid] = lb2[tid];
    if (tid < 16) B3[tid] = lb3[tid];
    if (tid < 3)  B4[tid] = lb4[tid];
    __syncthreads();

    int n = blockIdx.x * blockDim.x + tid;
    if (n >= N) return;
    const float* f = F + (long)n * 64;

    float h1[64];
    #pragma unroll
    for (int o = 0; o < 64; ++o) h1[o] = B1[o];
    for (int k = 0; k < 64; ++k) {
        float c = f[k];
        #pragma unroll
        for (int o = 0; o < 64; ++o) h1[o] = fmaf(c, W1[k][o], h1[o]);
    }
    float h2[32];
    #pragma unroll
    for (int o = 0; o < 32; ++o) h2[o] = B2[o];
    #pragma unroll
    for (int k = 0; k < 64; ++k) {
        float c = fmaxf(h1[k], 0.f);
        #pragma unroll
        for (int o = 0; o < 32; ++o) h2[o] = fmaf(c, W2[k][o], h2[o]);
    }
    float h3[16];
    #pragma unroll
    for (int o = 0; o < 16; ++o) h3[o] = B3[o];
    #pragma unroll
    for (int k = 0; k < 32; ++k) {
        float c = fmaxf(h2[k], 0.f);
        #pragma unroll
        for (int o = 0; o < 16; ++o) h3[o] = fmaf(c, W3[k][o], h3[o]);
    }
    float o0 = B4[0], o1 = B4[1], o2 = B4[2];
    #pragma unroll
    for (int k = 0; k < 16; ++k) {
        float c = fmaxf(h3[k], 0.f);
        o0 = fmaf(c, W4[k][0], o0);
        o1 = fmaf(c, W4[k][1], o1);
        o2 = fmaf(c, W4[k][2], o2);
    }
    out[(long)n * 3 + 0] = o0;
    out[(long)n * 3 + 1] = o1;
    out[(long)n * 3 + 2] = o2;
}

// ---------------------------------------------------------------------------
extern "C" void kernel_launch(void* const* d_in, const int* in_sizes, int n_in,
                              void* d_out, int out_size, void* d_ws, size_t ws_size,
                              hipStream_t stream)
{
    const float* x   = (const float*)d_in[0];
    const int*   ei  = (const int*)d_in[1];
    int N = in_sizes[0] / 3;
    int E = in_sizes[1] / 2;

    const float* w1a = (const float*)d_in[2];  const float* b1a = (const float*)d_in[3];
    const float* w1b = (const float*)d_in[4];  const float* b1b = (const float*)d_in[5];
    const float* w2a = (const float*)d_in[6];  const float* b2a = (const float*)d_in[7];
    const float* w2b = (const float*)d_in[8];  const float* b2b = (const float*)d_in[9];
    const float* w3a = (const float*)d_in[10]; const float* b3a = (const float*)d_in[11];
    const float* w3b = (const float*)d_in[12]; const float* b3b = (const float*)d_in[13];
    const float* bn1g = (const float*)d_in[14]; const float* bn1b = (const float*)d_in[15];
    const float* bn1m = (const float*)d_in[16]; const float* bn1v = (const float*)d_in[17];
    const float* bn2g = (const float*)d_in[18]; const float* bn2b = (const float*)d_in[19];
    const float* bn2m = (const float*)d_in[20]; const float* bn2v = (const float*)d_in[21];
    const float* bn3g = (const float*)d_in[22]; const float* bn3b = (const float*)d_in[23];
    const float* bn3m = (const float*)d_in[24]; const float* bn3v = (const float*)d_in[25];
    const float* lw1 = (const float*)d_in[26]; const float* lb1 = (const float*)d_in[27];
    const float* lw2 = (const float*)d_in[28]; const float* lb2 = (const float*)d_in[29];
    const float* lw3 = (const float*)d_in[30]; const float* lb3 = (const float*)d_in[31];
    const float* lw4 = (const float*)d_in[32]; const float* lb4 = (const float*)d_in[33];
    float* out = (float*)d_out;

    // workspace layout (256B aligned slices)
    char* ws = (char*)d_ws;
    size_t off = 0;
    auto alloc = [&](size_t bytes) { void* p = ws + off; off += (bytes + 255) & ~(size_t)255; return p; };
    int*   deg    = (int*)  alloc((size_t)N * sizeof(int));
    int*   bucket = (int*)  alloc((size_t)N * CAP * sizeof(int));
    float* U      = (float*)alloc((size_t)N * 64 * sizeof(float));
    float* V      = (float*)alloc((size_t)N * 64 * sizeof(float));
    float* F      = (float*)alloc((size_t)N * 64 * sizeof(float));
    (void)ws_size; (void)n_in; (void)out_size;

    hipMemsetAsync(deg, 0, (size_t)N * sizeof(int), stream);
    build_buckets<<<(E + 255) / 256, 256, 0, stream>>>(ei, E, deg, bucket);

    int uv_grid   = (2 * N + 255) / 256;
    int node_grid = ((size_t)N * 64 + 255) / 256;
    int nd_grid   = (N + 255) / 256;

    // layer 1
    uv_kernel<<<uv_grid, 256, 0, stream>>>(x, 3, 3, N, w1a, b1a, U, V);
    node_kernel<<<node_grid, 256, 0, stream>>>(U, V, deg, bucket, w1b, b1b,
                                               bn1g, bn1b, bn1m, bn1v, N, F);
    // layer 2
    uv_kernel<<<uv_grid, 256, 0, stream>>>(F, 64, 64, N, w2a, b2a, U, V);
    node_kernel<<<node_grid, 256, 0, stream>>>(U, V, deg, bucket, w2b, b2b,
                                               bn2g, bn2b, bn2m, bn2v, N, F);
    // layer 3
    uv_kernel<<<uv_grid, 256, 0, stream>>>(F, 64, 64, N, w3a, b3a, U, V);
    node_kernel<<<node_grid, 256, 0, stream>>>(U, V, deg, bucket, w3b, b3b,
                                               bn3g, bn3b, bn3m, bn3v, N, F);
    // head
    head_kernel<<<nd_grid, 256, 0, stream>>>(F, lw1, lb1, lw2, lb2, lw3, lb3,
                                             lw4, lb4, N, out);
}

// Round 4
// 592.219 us; speedup vs baseline: 1.9275x; 1.9275x over previous
//
#include <hip/hip_runtime.h>

#define CAP 64
#define BN_EPS 1e-5f

typedef _Float16 f16;
typedef _Float16 half8 __attribute__((ext_vector_type(8)));
typedef float f32x4 __attribute__((ext_vector_type(4)));

// ---------------- bucket build: CSR-lite with fixed capacity ----------------
__global__ __launch_bounds__(256) void build_buckets(
    const int* __restrict__ ei, int E,
    int* __restrict__ deg, int* __restrict__ bucket)
{
    int e = blockIdx.x * blockDim.x + threadIdx.x;
    if (e >= E) return;
    int src = ei[e];
    int dst = ei[E + e];
    int slot = atomicAdd(&deg[dst], 1);
    if (slot < CAP) bucket[dst * CAP + slot] = src;
}

// ---------------- per-node u/v precompute: u = f@(A-B)+ba, v = f@B ----------
// wa is [2K][64] row-major. thread t: node = t>>1, half = t&1 (0:u, 1:v).
// outputs U,V in f16 (feeds f16 MFMA fragments; rel err ~2^-12).
__global__ __launch_bounds__(256) void uv_kernel(
    const float* __restrict__ feat, int ldf, int K, int N,
    const float* __restrict__ wa, const float* __restrict__ ba,
    f16* __restrict__ U, f16* __restrict__ V)
{
    __shared__ float Wlds[2][64][64];
    __shared__ float blds[64];
    int tid = threadIdx.x;
    for (int idx = tid; idx < 2 * K * 64; idx += blockDim.x) {
        int half = idx / (K * 64);
        int rem = idx - half * (K * 64);
        int k = rem >> 6, o = rem & 63;
        float wB = wa[(K + k) * 64 + o];
        Wlds[half][k][o] = (half == 0) ? (wa[k * 64 + o] - wB) : wB;
    }
    if (tid < 64) blds[tid] = ba[tid];
    __syncthreads();

    int t = blockIdx.x * blockDim.x + tid;
    if (t >= 2 * N) return;
    int node = t >> 1, half = t & 1;

    float acc[64];
    #pragma unroll
    for (int o = 0; o < 64; ++o) acc[o] = (half == 0) ? blds[o] : 0.f;

    const float* f = feat + (long)node * ldf;
    for (int k = 0; k < K; ++k) {
        float c = f[k];
        #pragma unroll
        for (int o = 0; o < 64; ++o) acc[o] = fmaf(c, Wlds[half][k][o], acc[o]);
    }
    f16* dstp = (half == 0 ? U : V) + (long)node * 64;
    #pragma unroll
    for (int o = 0; o < 64; o += 8) {
        half8 h;
        #pragma unroll
        for (int j = 0; j < 8; ++j) h[j] = (f16)acc[o + j];
        *(half8*)(dstp + o) = h;
    }
}

// ---------------- node kernel: wave per node, MFMA edge-tile matvec ---------
// Per node: tiles of 16 edges; A[16][64] = relu(u+v) in f16; D = A@Wb via
// 8x mfma_f32_16x16x32_f16; mask padded rows -inf; max-reduce rows.
// A frag: lane holds A[row=lane&15][k=32*s+8*(lane>>4)+j]
// B frag: lane holds B[k=32*s+8*(lane>>4)+j][col=16*ct+(lane&15)]
// D frag: lane holds D[row=4*(lane>>4)+r][col=16*ct+(lane&15)]
__global__ __launch_bounds__(256) void node_kernel(
    const f16* __restrict__ U, const f16* __restrict__ V,
    const int* __restrict__ deg, const int* __restrict__ bucket,
    const float* __restrict__ wb, const float* __restrict__ bb,
    const float* __restrict__ bng, const float* __restrict__ bnb,
    const float* __restrict__ bnm, const float* __restrict__ bnv,
    int N, float* __restrict__ Fout)
{
    const int lane = threadIdx.x & 63;
    const int r16 = lane >> 4, c16 = lane & 15;
    const int wid = (blockIdx.x * blockDim.x + threadIdx.x) >> 6;
    const int nwaves = (gridDim.x * blockDim.x) >> 6;

    // B fragments (Wb in f16), loaded once per wave, amortized over node chunk
    half8 bfrag[8]; // [ct*2+s]
    #pragma unroll
    for (int ct = 0; ct < 4; ++ct)
        #pragma unroll
        for (int s = 0; s < 2; ++s) {
            half8 h;
            #pragma unroll
            for (int j = 0; j < 8; ++j) {
                int k = 32 * s + 8 * r16 + j;
                h[j] = (f16)wb[k * 64 + 16 * ct + c16];
            }
            bfrag[ct * 2 + s] = h;
        }

    const float bbv = bb[lane];
    const float g = bng[lane], be = bnb[lane];
    const float rs = rsqrtf(bnv[lane] + BN_EPS), mm = bnm[lane];

    int chunk = (N + nwaves - 1) / nwaves;
    int n0 = wid * chunk;
    int n1 = n0 + chunk; if (n1 > N) n1 = N;

    for (int node = n0; node < n1; ++node) {
        int d = deg[node]; if (d > CAP) d = CAP;

        const half8* urow = (const half8*)(U + (long)node * 64);
        half8 u0 = urow[r16];       // k-step 0 slice
        half8 u1 = urow[4 + r16];   // k-step 1 slice

        float m0 = -INFINITY, m1 = -INFINITY, m2 = -INFINITY, m3 = -INFINITY;
        int ntile = (d + 15) >> 4;
        for (int t = 0; t < ntile; ++t) {
            int slot = t * 16 + c16;
            int src = (slot < d) ? bucket[node * CAP + slot] : 0;
            const half8* vrow = (const half8*)(V + (long)src * 64);
            half8 a0 = vrow[r16] + u0;
            half8 a1 = vrow[4 + r16] + u1;
            #pragma unroll
            for (int j = 0; j < 8; ++j) {
                a0[j] = a0[j] > (f16)0 ? a0[j] : (f16)0;
                a1[j] = a1[j] > (f16)0 ? a1[j] : (f16)0;
            }
            const f32x4 z = {0.f, 0.f, 0.f, 0.f};
            #pragma unroll
            for (int ct = 0; ct < 4; ++ct) {
                f32x4 acc = __builtin_amdgcn_mfma_f32_16x16x32_f16(a0, bfrag[ct * 2 + 0], z, 0, 0, 0);
                acc = __builtin_amdgcn_mfma_f32_16x16x32_f16(a1, bfrag[ct * 2 + 1], acc, 0, 0, 0);
                float mx = -INFINITY;
                #pragma unroll
                for (int r = 0; r < 4; ++r) {
                    int row = t * 16 + r16 * 4 + r;   // edge slot of this D element
                    float val = (row < d) ? acc[r] : -INFINITY;
                    mx = fmaxf(mx, val);
                }
                mx = fmaxf(mx, __shfl_xor(mx, 16));
                mx = fmaxf(mx, __shfl_xor(mx, 32));
                if (ct == 0) m0 = fmaxf(m0, mx);
                else if (ct == 1) m1 = fmaxf(m1, mx);
                else if (ct == 2) m2 = fmaxf(m2, mx);
                else m3 = fmaxf(m3, mx);
            }
        }
        // lane L's channel = L: pick col-tile L>>4 (all lanes hold every tile's col max)
        float sel = (r16 == 0) ? m0 : (r16 == 1) ? m1 : (r16 == 2) ? m2 : m3;
        float aggv = (d > 0) ? sel + bbv : 0.f;
        float bn = (aggv - mm) * rs * g + be;
        Fout[(long)node * 64 + lane] = fmaxf(bn, 0.f);
    }
}

// ---------------- dense head: thread per node -------------------------------
__global__ __launch_bounds__(256) void head_kernel(
    const float* __restrict__ F,
    const float* __restrict__ lw1, const float* __restrict__ lb1,
    const float* __restrict__ lw2, const float* __restrict__ lb2,
    const float* __restrict__ lw3, const float* __restrict__ lb3,
    const float* __restrict__ lw4, const float* __restrict__ lb4,
    int N, float* __restrict__ out)
{
    __shared__ float W1[64][64];
    __shared__ float W2[64][32];
    __shared__ float W3[32][16];
    __shared__ float W4[16][3];
    __shared__ float B1[64], B2[32], B3[16], B4[3];
    int tid = threadIdx.x;
    for (int i = tid; i < 64 * 64; i += blockDim.x) W1[i >> 6][i & 63] = lw1[i];
    for (int i = tid; i < 64 * 32; i += blockDim.x) W2[i >> 5][i & 31] = lw2[i];
    for (int i = tid; i < 32 * 16; i += blockDim.x) W3[i >> 4][i & 15] = lw3[i];
    for (int i = tid; i < 16 * 3;  i += blockDim.x) W4[i / 3][i % 3]  = lw4[i];
    if (tid < 64) B1[tid] = lb1[tid];
    if (tid < 32) B2[tid] = lb2[tid];
    if (tid < 16) B3[tid] = lb3[tid];
    if (tid < 3)  B4[tid] = lb4[tid];
    __syncthreads();

    int n = blockIdx.x * blockDim.x + tid;
    if (n >= N) return;
    const float* f = F + (long)n * 64;

    float h1[64];
    #pragma unroll
    for (int o = 0; o < 64; ++o) h1[o] = B1[o];
    for (int k = 0; k < 64; ++k) {
        float c = f[k];
        #pragma unroll
        for (int o = 0; o < 64; ++o) h1[o] = fmaf(c, W1[k][o], h1[o]);
    }
    float h2[32];
    #pragma unroll
    for (int o = 0; o < 32; ++o) h2[o] = B2[o];
    #pragma unroll
    for (int k = 0; k < 64; ++k) {
        float c = fmaxf(h1[k], 0.f);
        #pragma unroll
        for (int o = 0; o < 32; ++o) h2[o] = fmaf(c, W2[k][o], h2[o]);
    }
    float h3[16];
    #pragma unroll
    for (int o = 0; o < 16; ++o) h3[o] = B3[o];
    #pragma unroll
    for (int k = 0; k < 32; ++k) {
        float c = fmaxf(h2[k], 0.f);
        #pragma unroll
        for (int o = 0; o < 16; ++o) h3[o] = fmaf(c, W3[k][o], h3[o]);
    }
    float o0 = B4[0], o1 = B4[1], o2 = B4[2];
    #pragma unroll
    for (int k = 0; k < 16; ++k) {
        float c = fmaxf(h3[k], 0.f);
        o0 = fmaf(c, W4[k][0], o0);
        o1 = fmaf(c, W4[k][1], o1);
        o2 = fmaf(c, W4[k][2], o2);
    }
    out[(long)n * 3 + 0] = o0;
    out[(long)n * 3 + 1] = o1;
    out[(long)n * 3 + 2] = o2;
}

// ---------------------------------------------------------------------------
extern "C" void kernel_launch(void* const* d_in, const int* in_sizes, int n_in,
                              void* d_out, int out_size, void* d_ws, size_t ws_size,
                              hipStream_t stream)
{
    const float* x   = (const float*)d_in[0];
    const int*   ei  = (const int*)d_in[1];
    int N = in_sizes[0] / 3;
    int E = in_sizes[1] / 2;

    const float* w1a = (const float*)d_in[2];  const float* b1a = (const float*)d_in[3];
    const float* w1b = (const float*)d_in[4];  const float* b1b = (const float*)d_in[5];
    const float* w2a = (const float*)d_in[6];  const float* b2a = (const float*)d_in[7];
    const float* w2b = (const float*)d_in[8];  const float* b2b = (const float*)d_in[9];
    const float* w3a = (const float*)d_in[10]; const float* b3a = (const float*)d_in[11];
    const float* w3b = (const float*)d_in[12]; const float* b3b = (const float*)d_in[13];
    const float* bn1g = (const float*)d_in[14]; const float* bn1b = (const float*)d_in[15];
    const float* bn1m = (const float*)d_in[16]; const float* bn1v = (const float*)d_in[17];
    const float* bn2g = (const float*)d_in[18]; const float* bn2b = (const float*)d_in[19];
    const float* bn2m = (const float*)d_in[20]; const float* bn2v = (const float*)d_in[21];
    const float* bn3g = (const float*)d_in[22]; const float* bn3b = (const float*)d_in[23];
    const float* bn3m = (const float*)d_in[24]; const float* bn3v = (const float*)d_in[25];
    const float* lw1 = (const float*)d_in[26]; const float* lb1 = (const float*)d_in[27];
    const float* lw2 = (const float*)d_in[28]; const float* lb2 = (const float*)d_in[29];
    const float* lw3 = (const float*)d_in[30]; const float* lb3 = (const float*)d_in[31];
    const float* lw4 = (const float*)d_in[32]; const float* lb4 = (const float*)d_in[33];
    float* out = (float*)d_out;

    // workspace layout (256B aligned slices)
    char* ws = (char*)d_ws;
    size_t off = 0;
    auto alloc = [&](size_t bytes) { void* p = ws + off; off += (bytes + 255) & ~(size_t)255; return p; };
    int*   deg    = (int*)  alloc((size_t)N * sizeof(int));
    int*   bucket = (int*)  alloc((size_t)N * CAP * sizeof(int));
    f16*   U      = (f16*)  alloc((size_t)N * 64 * sizeof(f16));
    f16*   V      = (f16*)  alloc((size_t)N * 64 * sizeof(f16));
    float* F      = (float*)alloc((size_t)N * 64 * sizeof(float));
    (void)ws_size; (void)n_in; (void)out_size;

    hipMemsetAsync(deg, 0, (size_t)N * sizeof(int), stream);
    build_buckets<<<(E + 255) / 256, 256, 0, stream>>>(ei, E, deg, bucket);

    int uv_grid   = (2 * N + 255) / 256;
    int node_blocks = 2048;            // 8192 waves, ~13-node chunks
    int nd_grid   = (N + 255) / 256;

    // layer 1
    uv_kernel<<<uv_grid, 256, 0, stream>>>(x, 3, 3, N, w1a, b1a, U, V);
    node_kernel<<<node_blocks, 256, 0, stream>>>(U, V, deg, bucket, w1b, b1b,
                                                 bn1g, bn1b, bn1m, bn1v, N, F);
    // layer 2
    uv_kernel<<<uv_grid, 256, 0, stream>>>(F, 64, 64, N, w2a, b2a, U, V);
    node_kernel<<<node_blocks, 256, 0, stream>>>(U, V, deg, bucket, w2b, b2b,
                                                 bn2g, bn2b, bn2m, bn2v, N, F);
    // layer 3
    uv_kernel<<<uv_grid, 256, 0, stream>>>(F, 64, 64, N, w3a, b3a, U, V);
    node_kernel<<<node_blocks, 256, 0, stream>>>(U, V, deg, bucket, w3b, b3b,
                                                 bn3g, bn3b, bn3m, bn3v, N, F);
    // head
    head_kernel<<<nd_grid, 256, 0, stream>>>(F, lw1, lb1, lw2, lb2, lw3, lb3,
                                             lw4, lb4, N, out);
}

// Round 5
// 551.184 us; speedup vs baseline: 2.0710x; 1.0744x over previous
//
#include <hip/hip_runtime.h>

#define CAP 64
#define BN_EPS 1e-5f

typedef _Float16 f16;
typedef _Float16 half8 __attribute__((ext_vector_type(8)));
typedef float f32x4 __attribute__((ext_vector_type(4)));

// ---------------- bucket build: CSR-lite with fixed capacity ----------------
__global__ __launch_bounds__(256) void build_buckets(
    const int* __restrict__ ei, int E,
    int* __restrict__ deg, int* __restrict__ bucket)
{
    int e = blockIdx.x * blockDim.x + threadIdx.x;
    if (e >= E) return;
    int src = ei[e];
    int dst = ei[E + e];
    int slot = atomicAdd(&deg[dst], 1);
    if (slot < CAP) bucket[dst * CAP + slot] = src;
}

// ---------------- per-node u/v precompute: u = f@(A-B)+ba, v = f@B ----------
__global__ __launch_bounds__(256) void uv_kernel(
    const float* __restrict__ feat, int ldf, int K, int N,
    const float* __restrict__ wa, const float* __restrict__ ba,
    f16* __restrict__ U, f16* __restrict__ V)
{
    __shared__ float Wlds[2][64][64];
    __shared__ float blds[64];
    int tid = threadIdx.x;
    for (int idx = tid; idx < 2 * K * 64; idx += blockDim.x) {
        int half = idx / (K * 64);
        int rem = idx - half * (K * 64);
        int k = rem >> 6, o = rem & 63;
        float wB = wa[(K + k) * 64 + o];
        Wlds[half][k][o] = (half == 0) ? (wa[k * 64 + o] - wB) : wB;
    }
    if (tid < 64) blds[tid] = ba[tid];
    __syncthreads();

    int t = blockIdx.x * blockDim.x + tid;
    if (t >= 2 * N) return;
    int node = t >> 1, half = t & 1;

    float acc[64];
    #pragma unroll
    for (int o = 0; o < 64; ++o) acc[o] = (half == 0) ? blds[o] : 0.f;

    const float* f = feat + (long)node * ldf;
    for (int k = 0; k < K; ++k) {
        float c = f[k];
        #pragma unroll
        for (int o = 0; o < 64; ++o) acc[o] = fmaf(c, Wlds[half][k][o], acc[o]);
    }
    f16* dstp = (half == 0 ? U : V) + (long)node * 64;
    #pragma unroll
    for (int o = 0; o < 64; o += 8) {
        half8 h;
        #pragma unroll
        for (int j = 0; j < 8; ++j) h[j] = (f16)acc[o + j];
        *(half8*)(dstp + o) = h;
    }
}

// ---------------- node kernel: wave per node, MFMA, 2-deep pipeline ---------
// A frag: lane holds A[row=lane&15][k=32*s+8*(lane>>4)+j]
// B frag: lane holds B[k=32*s+8*(lane>>4)+j][col=16*ct+(lane&15)]
// D frag: lane holds D[row=4*(lane>>4)+r][col=16*ct+(lane&15)]
__global__ __launch_bounds__(256) void node_kernel(
    const f16* __restrict__ U, const f16* __restrict__ V,
    const int* __restrict__ deg, const int* __restrict__ bucket,
    const float* __restrict__ wb, const float* __restrict__ bb,
    const float* __restrict__ bng, const float* __restrict__ bnb,
    const float* __restrict__ bnm, const float* __restrict__ bnv,
    int N, float* __restrict__ Fout)
{
    const int lane = threadIdx.x & 63;
    const int r16 = lane >> 4, c16 = lane & 15;
    const int wid = (blockIdx.x * blockDim.x + threadIdx.x) >> 6;
    const int nwaves = (gridDim.x * blockDim.x) >> 6;

    half8 bfrag[8]; // [ct*2+s]
    #pragma unroll
    for (int ct = 0; ct < 4; ++ct)
        #pragma unroll
        for (int s = 0; s < 2; ++s) {
            half8 h;
            #pragma unroll
            for (int j = 0; j < 8; ++j) {
                int k = 32 * s + 8 * r16 + j;
                h[j] = (f16)wb[k * 64 + 16 * ct + c16];
            }
            bfrag[ct * 2 + s] = h;
        }

    const float bbv = bb[lane];
    const float g = bng[lane], be = bnb[lane];
    const float rs = rsqrtf(bnv[lane] + BN_EPS), mm = bnm[lane];

    int chunk = (N + nwaves - 1) / nwaves;
    int n0 = wid * chunk;
    int n1 = n0 + chunk; if (n1 > N) n1 = N;
    if (n0 >= n1) return;

    // block-load this chunk's degrees (chunk <= 64), access via shfl
    int dval = 0;
    if (lane < n1 - n0) dval = deg[n0 + lane];
    dval = dval > CAP ? CAP : dval;

    // prologue: bucket row (tile0) + gather for n0; bucket row for n0+1
    int bkt_cur = bucket[(long)n0 * CAP + c16];
    int np = (n0 + 1 < n1) ? n0 + 1 : n0;
    int bkt_nxt = bucket[(long)np * CAP + c16];

    unsigned s0u = (unsigned)bkt_cur < (unsigned)N ? (unsigned)bkt_cur : 0u;
    const half8* vr = (const half8*)(V + (long)s0u * 64);
    half8 vA = vr[r16], vB = vr[4 + r16];
    const half8* ur = (const half8*)(U + (long)n0 * 64);
    half8 uA = ur[r16], uB = ur[4 + r16];

    for (int node = n0; node < n1; ++node) {
        // -- issue next node's V gather (bucket row already in flight/landed) --
        unsigned s1u = (unsigned)bkt_nxt < (unsigned)N ? (unsigned)bkt_nxt : 0u;
        const half8* vr1 = (const half8*)(V + (long)s1u * 64);
        half8 vA2 = vr1[r16], vB2 = vr1[4 + r16];
        // -- issue node+2's bucket row --
        int nn = (node + 2 < n1) ? node + 2 : n1 - 1;
        int bkt_fut = bucket[(long)nn * CAP + c16];
        // -- issue node+1's U row --
        int np1 = (node + 1 < n1) ? node + 1 : node;
        const half8* ur1 = (const half8*)(U + (long)np1 * 64);
        half8 uA2 = ur1[r16], uB2 = ur1[4 + r16];

        int d = __shfl(dval, node - n0);

        float m0 = -INFINITY, m1 = -INFINITY, m2 = -INFINITY, m3 = -INFINITY;
        int ntile = (d + 15) >> 4;

        if (ntile > 0) {
            // tile 0: data already gathered (vA/vB)
            half8 a0 = vA + uA;
            half8 a1 = vB + uB;
            #pragma unroll
            for (int j = 0; j < 8; ++j) {
                a0[j] = a0[j] > (f16)0 ? a0[j] : (f16)0;
                a1[j] = a1[j] > (f16)0 ? a1[j] : (f16)0;
            }
            const f32x4 z = {0.f, 0.f, 0.f, 0.f};
            #pragma unroll
            for (int ct = 0; ct < 4; ++ct) {
                f32x4 acc = __builtin_amdgcn_mfma_f32_16x16x32_f16(a0, bfrag[ct * 2 + 0], z, 0, 0, 0);
                acc = __builtin_amdgcn_mfma_f32_16x16x32_f16(a1, bfrag[ct * 2 + 1], acc, 0, 0, 0);
                float mx = -INFINITY;
                #pragma unroll
                for (int r = 0; r < 4; ++r) {
                    int row = r16 * 4 + r;
                    float val = (row < d) ? acc[r] : -INFINITY;
                    mx = fmaxf(mx, val);
                }
                mx = fmaxf(mx, __shfl_xor(mx, 16));
                mx = fmaxf(mx, __shfl_xor(mx, 32));
                if (ct == 0) m0 = fmaxf(m0, mx);
                else if (ct == 1) m1 = fmaxf(m1, mx);
                else if (ct == 2) m2 = fmaxf(m2, mx);
                else m3 = fmaxf(m3, mx);
            }
        }
        // rare tiles (d > 16): serial path
        for (int t = 1; t < ntile; ++t) {
            int bkt = bucket[(long)node * CAP + t * 16 + c16];
            unsigned su = (unsigned)bkt < (unsigned)N ? (unsigned)bkt : 0u;
            const half8* vrt = (const half8*)(V + (long)su * 64);
            half8 a0 = vrt[r16] + uA;
            half8 a1 = vrt[4 + r16] + uB;
            #pragma unroll
            for (int j = 0; j < 8; ++j) {
                a0[j] = a0[j] > (f16)0 ? a0[j] : (f16)0;
                a1[j] = a1[j] > (f16)0 ? a1[j] : (f16)0;
            }
            const f32x4 z = {0.f, 0.f, 0.f, 0.f};
            #pragma unroll
            for (int ct = 0; ct < 4; ++ct) {
                f32x4 acc = __builtin_amdgcn_mfma_f32_16x16x32_f16(a0, bfrag[ct * 2 + 0], z, 0, 0, 0);
                acc = __builtin_amdgcn_mfma_f32_16x16x32_f16(a1, bfrag[ct * 2 + 1], acc, 0, 0, 0);
                float mx = -INFINITY;
                #pragma unroll
                for (int r = 0; r < 4; ++r) {
                    int row = t * 16 + r16 * 4 + r;
                    float val = (row < d) ? acc[r] : -INFINITY;
                    mx = fmaxf(mx, val);
                }
                mx = fmaxf(mx, __shfl_xor(mx, 16));
                mx = fmaxf(mx, __shfl_xor(mx, 32));
                if (ct == 0) m0 = fmaxf(m0, mx);
                else if (ct == 1) m1 = fmaxf(m1, mx);
                else if (ct == 2) m2 = fmaxf(m2, mx);
                else m3 = fmaxf(m3, mx);
            }
        }

        float sel = (r16 == 0) ? m0 : (r16 == 1) ? m1 : (r16 == 2) ? m2 : m3;
        float aggv = (d > 0) ? sel + bbv : 0.f;
        float bn = (aggv - mm) * rs * g + be;
        Fout[(long)node * 64 + lane] = fmaxf(bn, 0.f);

        // rotate pipeline registers
        vA = vA2; vB = vB2; uA = uA2; uB = uB2; bkt_nxt = bkt_fut;
    }
}

// ---------------- dense head: thread per node -------------------------------
__global__ __launch_bounds__(256) void head_kernel(
    const float* __restrict__ F,
    const float* __restrict__ lw1, const float* __restrict__ lb1,
    const float* __restrict__ lw2, const float* __restrict__ lb2,
    const float* __restrict__ lw3, const float* __restrict__ lb3,
    const float* __restrict__ lw4, const float* __restrict__ lb4,
    int N, float* __restrict__ out)
{
    __shared__ float W1[64][64];
    __shared__ float W2[64][32];
    __shared__ float W3[32][16];
    __shared__ float W4[16][3];
    __shared__ float B1[64], B2[32], B3[16], B4[3];
    int tid = threadIdx.x;
    for (int i = tid; i < 64 * 64; i += blockDim.x) W1[i >> 6][i & 63] = lw1[i];
    for (int i = tid; i < 64 * 32; i += blockDim.x) W2[i >> 5][i & 31] = lw2[i];
    for (int i = tid; i < 32 * 16; i += blockDim.x) W3[i >> 4][i & 15] = lw3[i];
    for (int i = tid; i < 16 * 3;  i += blockDim.x) W4[i / 3][i % 3]  = lw4[i];
    if (tid < 64) B1[tid] = lb1[tid];
    if (tid < 32) B2[tid] = lb2[tid];
    if (tid < 16) B3[tid] = lb3[tid];
    if (tid < 3)  B4[tid] = lb4[tid];
    __syncthreads();

    int n = blockIdx.x * blockDim.x + tid;
    if (n >= N) return;
    const float* f = F + (long)n * 64;

    float h1[64];
    #pragma unroll
    for (int o = 0; o < 64; ++o) h1[o] = B1[o];
    for (int k = 0; k < 64; ++k) {
        float c = f[k];
        #pragma unroll
        for (int o = 0; o < 64; ++o) h1[o] = fmaf(c, W1[k][o], h1[o]);
    }
    float h2[32];
    #pragma unroll
    for (int o = 0; o < 32; ++o) h2[o] = B2[o];
    #pragma unroll
    for (int k = 0; k < 64; ++k) {
        float c = fmaxf(h1[k], 0.f);
        #pragma unroll
        for (int o = 0; o < 32; ++o) h2[o] = fmaf(c, W2[k][o], h2[o]);
    }
    float h3[16];
    #pragma unroll
    for (int o = 0; o < 16; ++o) h3[o] = B3[o];
    #pragma unroll
    for (int k = 0; k < 32; ++k) {
        float c = fmaxf(h2[k], 0.f);
        #pragma unroll
        for (int o = 0; o < 16; ++o) h3[o] = fmaf(c, W3[k][o], h3[o]);
    }
    float o0 = B4[0], o1 = B4[1], o2 = B4[2];
    #pragma unroll
    for (int k = 0; k < 16; ++k) {
        float c = fmaxf(h3[k], 0.f);
        o0 = fmaf(c, W4[k][0], o0);
        o1 = fmaf(c, W4[k][1], o1);
        o2 = fmaf(c, W4[k][2], o2);
    }
    out[(long)n * 3 + 0] = o0;
    out[(long)n * 3 + 1] = o1;
    out[(long)n * 3 + 2] = o2;
}

// ---------------------------------------------------------------------------
extern "C" void kernel_launch(void* const* d_in, const int* in_sizes, int n_in,
                              void* d_out, int out_size, void* d_ws, size_t ws_size,
                              hipStream_t stream)
{
    const float* x   = (const float*)d_in[0];
    const int*   ei  = (const int*)d_in[1];
    int N = in_sizes[0] / 3;
    int E = in_sizes[1] / 2;

    const float* w1a = (const float*)d_in[2];  const float* b1a = (const float*)d_in[3];
    const float* w1b = (const float*)d_in[4];  const float* b1b = (const float*)d_in[5];
    const float* w2a = (const float*)d_in[6];  const float* b2a = (const float*)d_in[7];
    const float* w2b = (const float*)d_in[8];  const float* b2b = (const float*)d_in[9];
    const float* w3a = (const float*)d_in[10]; const float* b3a = (const float*)d_in[11];
    const float* w3b = (const float*)d_in[12]; const float* b3b = (const float*)d_in[13];
    const float* bn1g = (const float*)d_in[14]; const float* bn1b = (const float*)d_in[15];
    const float* bn1m = (const float*)d_in[16]; const float* bn1v = (const float*)d_in[17];
    const float* bn2g = (const float*)d_in[18]; const float* bn2b = (const float*)d_in[19];
    const float* bn2m = (const float*)d_in[20]; const float* bn2v = (const float*)d_in[21];
    const float* bn3g = (const float*)d_in[22]; const float* bn3b = (const float*)d_in[23];
    const float* bn3m = (const float*)d_in[24]; const float* bn3v = (const float*)d_in[25];
    const float* lw1 = (const float*)d_in[26]; const float* lb1 = (const float*)d_in[27];
    const float* lw2 = (const float*)d_in[28]; const float* lb2 = (const float*)d_in[29];
    const float* lw3 = (const float*)d_in[30]; const float* lb3 = (const float*)d_in[31];
    const float* lw4 = (const float*)d_in[32]; const float* lb4 = (const float*)d_in[33];
    float* out = (float*)d_out;

    // workspace layout (256B aligned slices)
    char* ws = (char*)d_ws;
    size_t off = 0;
    auto alloc = [&](size_t bytes) { void* p = ws + off; off += (bytes + 255) & ~(size_t)255; return p; };
    int*   deg    = (int*)  alloc((size_t)N * sizeof(int));
    int*   bucket = (int*)  alloc((size_t)N * CAP * sizeof(int));
    f16*   U      = (f16*)  alloc((size_t)N * 64 * sizeof(f16));
    f16*   V      = (f16*)  alloc((size_t)N * 64 * sizeof(f16));
    float* F      = (float*)alloc((size_t)N * 64 * sizeof(float));
    (void)ws_size; (void)n_in; (void)out_size;

    hipMemsetAsync(deg, 0, (size_t)N * sizeof(int), stream);
    build_buckets<<<(E + 255) / 256, 256, 0, stream>>>(ei, E, deg, bucket);

    int uv_grid   = (2 * N + 255) / 256;
    int node_blocks = 2048;            // 8192 waves, ~13-node chunks
    int nd_grid   = (N + 255) / 256;

    // layer 1
    uv_kernel<<<uv_grid, 256, 0, stream>>>(x, 3, 3, N, w1a, b1a, U, V);
    node_kernel<<<node_blocks, 256, 0, stream>>>(U, V, deg, bucket, w1b, b1b,
                                                 bn1g, bn1b, bn1m, bn1v, N, F);
    // layer 2
    uv_kernel<<<uv_grid, 256, 0, stream>>>(F, 64, 64, N, w2a, b2a, U, V);
    node_kernel<<<node_blocks, 256, 0, stream>>>(U, V, deg, bucket, w2b, b2b,
                                                 bn2g, bn2b, bn2m, bn2v, N, F);
    // layer 3
    uv_kernel<<<uv_grid, 256, 0, stream>>>(F, 64, 64, N, w3a, b3a, U, V);
    node_kernel<<<node_blocks, 256, 0, stream>>>(U, V, deg, bucket, w3b, b3b,
                                                 bn3g, bn3b, bn3m, bn3v, N, F);
    // head
    head_kernel<<<nd_grid, 256, 0, stream>>>(F, lw1, lb1, lw2, lb2, lw3, lb3,
                                             lw4, lb4, N, out);
}